// Round 7
// baseline (222.850 us; speedup 1.0000x reference)
//
#include <hip/hip_runtime.h>
#include <stdint.h>

#define NB 16
#define NQ 100
#define QP 112   // Q padded to 7*16; rows 100..110 dummy-ones, row 111 = mask-sum row
#define NG 16384
#define NT 50
#define TP 64    // T padded: 50..62 zero, 63 = ones column (Sum(m), Sum(sigmoid))
#define NL 21
#define NCH 32   // K-split chunks; K per block = 512
#define CH 512

// ws layout (bytes)
#define SZ_P     ((size_t)NCH*NB*7*1024*4)     // 14,680,064 per partial array
#define OFF_PM   0u
#define OFF_PS   (SZ_P)
#define OFF_RM   (2*SZ_P)                      // reduced [b][wv][1024]
#define SZ_R     ((size_t)NB*7*1024*4)         // 458,752
#define OFF_RS   (OFF_RM + SZ_R)
#define OFF_SSP  (OFF_RS + SZ_R)
#define SZ_SSP   (NB*QP*4u)                    // 7,168
#define NEED_WS  (OFF_SSP + SZ_SSP)

typedef __bf16 bf16x8 __attribute__((ext_vector_type(8)));
typedef float f32x4 __attribute__((ext_vector_type(4)));
union Frag { uint32_t u[4]; bf16x8 v; };

__device__ __forceinline__ uint32_t pack_bf16(float a, float b) {
  uint32_t ua = __float_as_uint(a), ub = __float_as_uint(b);
  ua = (ua + 0x7FFFu + ((ua >> 16) & 1u)) >> 16;
  ub = (ub + 0x7FFFu + ((ub >> 16) & 1u)) & 0xFFFF0000u;
  return ua | ub;
}

// ---------------------------------------------------------------------------
// kernel1: per block (b, chunk of K=512): stage mask slice -> bf16 MFMA
// B-fragments in LDS (one barrier), 7 waves (16 q-rows each) run dual GEMM
// (m·maskT, sigmoid(m)·maskT) + softplus-log row sums. Partials streamed.
// K-loop: 4 groups x 4 steps; all 8 A-loads of a group issued before use
// (MLP=8; lane slice for step s is at g*128 + s*32 + {0,4}, arow carries lg*8;
// max offset = 384+96+4+3+24 = 511 — in bounds).
// ---------------------------------------------------------------------------
__global__ __launch_bounds__(448) void gemm_part(
    const float* __restrict__ m, const float* __restrict__ mask,
    float* __restrict__ ssp, float* __restrict__ pdm,
    float* __restrict__ pds) {
  __shared__ __align__(16) uint32_t bfr[16 * 4 * 64 * 4];   // 64 KB
  int blk = blockIdx.x;
  int chunk = blk & (NCH - 1), b = blk >> 5;
  int tid = threadIdx.x;

  // ---- stage B: 16 threads per t-row; 16 thr x 16B = 256B contiguous loads
  {
    int sub = tid & 15, tb = tid >> 4;           // tb 0..27
    uint2* U2 = (uint2*)bfr;
    int lgs = (sub & 7) >> 1, half = sub & 1;
    for (int t = tb; t < 64; t += 28) {
      int nt = t >> 4;
      if (t < NT) {
        const float* src = mask + ((size_t)(b*NT + t))*NG + chunk*CH + sub*4;
#pragma unroll
        for (int i = 0; i < 8; ++i) {
          float4 f = *(const float4*)(src + i*64);
          int ks = (sub >> 3) + i*2;
          uint2 pk; pk.x = pack_bf16(f.x, f.y); pk.y = pack_bf16(f.z, f.w);
          U2[((ks*4 + nt)*64 + lgs*16 + (t & 15))*2 + half] = pk;
        }
      } else {
        uint32_t c = (t == 63) ? 0x3F803F80u : 0u;
        uint2 pk; pk.x = c; pk.y = c;
#pragma unroll
        for (int i = 0; i < 8; ++i) {
          int ks = (sub >> 3) + i*2;
          U2[((ks*4 + nt)*64 + lgs*16 + (t & 15))*2 + half] = pk;
        }
      }
    }
  }
  __syncthreads();

  // ---- compute ----
  int lane = tid & 63, wv = tid >> 6;            // wv = q-tile 0..6
  int row16 = lane & 15, lg = lane >> 4;
  int q0 = wv * 16;
  int qrow = q0 + row16;
  bool pad = qrow > NQ - 1;                      // rows 100..111 -> ones rows
  const float* arow = m + (size_t)(b*NQ + (pad ? 0 : qrow))*NG + chunk*CH + lg*8;
  const bf16x8* BF = (const bf16x8*)bfr;

  f32x4 accm[4], accs[4];
#pragma unroll
  for (int nt = 0; nt < 4; ++nt) { accm[nt] = (f32x4)(0.f); accs[nt] = (f32x4)(0.f); }
  float sl = 0.f;                                // sum log2(1+e^-x)

#pragma unroll
  for (int g = 0; g < 4; ++g) {                  // 4 groups x 4 K-steps
    float4 ra[8];
    if (!pad) {
#pragma unroll
      for (int s = 0; s < 4; ++s) {              // 8 loads issued before use
        ra[2*s]   = *(const float4*)(arow + g*128 + s*32);
        ra[2*s+1] = *(const float4*)(arow + g*128 + s*32 + 4);
      }
    } else {
#pragma unroll
      for (int i = 0; i < 8; ++i) ra[i] = make_float4(0.f, 0.f, 0.f, 0.f);
    }
#pragma unroll
    for (int s = 0; s < 4; ++s) {
      int ks = g*4 + s;
      float av[8] = {ra[2*s].x, ra[2*s].y, ra[2*s].z, ra[2*s].w,
                     ra[2*s+1].x, ra[2*s+1].y, ra[2*s+1].z, ra[2*s+1].w};
      Frag mf, sf;
#pragma unroll
      for (int j = 0; j < 8; j += 2) {
        float x0 = pad ? 1.f : av[j];
        float x1 = pad ? 1.f : av[j+1];
        float e0 = __builtin_amdgcn_exp2f(x0 * -1.442695041f);
        float e1 = __builtin_amdgcn_exp2f(x1 * -1.442695041f);
        float u0 = 1.f + e0, u1 = 1.f + e1;
        float r0 = __builtin_amdgcn_rcpf(u0), r1 = __builtin_amdgcn_rcpf(u1);
        sl += __builtin_amdgcn_logf(u0) + __builtin_amdgcn_logf(u1);
        mf.u[j >> 1] = pack_bf16(x0, x1);
        sf.u[j >> 1] = pack_bf16(r0, r1);
      }
#pragma unroll
      for (int nt = 0; nt < 4; ++nt) {
        bf16x8 bb = BF[(ks*4 + nt)*64 + lane];   // linear -> conflict-free
        accm[nt] = __builtin_amdgcn_mfma_f32_16x16x32_bf16(mf.v, bb, accm[nt], 0, 0, 0);
        accs[nt] = __builtin_amdgcn_mfma_f32_16x16x32_bf16(sf.v, bb, accs[nt], 0, 0, 0);
      }
    }
  }

  // softplus-log row sums: lanes {l, l^16, l^32, l^48} share a q-row
  sl += __shfl_xor(sl, 16); sl += __shfl_xor(sl, 32);
  if (lg == 0) atomicAdd(&ssp[b*QP + q0 + row16], sl);

  // streamed partial store, fragment-native order (16 f32/lane, coalesced)
  size_t base = ((size_t)(b*NCH + chunk)*7 + wv)*1024 + lane*16;
#pragma unroll
  for (int nt = 0; nt < 4; ++nt) {
    *(f32x4*)(pdm + base + nt*4) = accm[nt];
    *(f32x4*)(pds + base + nt*4) = accs[nt];
  }
}

// ---------------------------------------------------------------------------
// kernel2: reduce partials over 32 chunks (coalesced both sides)
// ---------------------------------------------------------------------------
__global__ __launch_bounds__(256) void reduce_k(
    const float* __restrict__ pdm, const float* __restrict__ pds,
    float* __restrict__ rm, float* __restrict__ rs) {
  int idx = blockIdx.x*256 + threadIdx.x;        // 114,688 total = 448 blocks
  int b = idx / 7168, rem = idx % 7168;
  size_t bp = (size_t)b*NCH*7168 + rem;
  float sm = 0.f, ss = 0.f;
#pragma unroll
  for (int ch = 0; ch < NCH; ++ch) {
    sm += pdm[bp + (size_t)ch*7168];
    ss += pds[bp + (size_t)ch*7168];
  }
  rm[idx] = sm;
  rs[idx] = ss;
}

// ---------------------------------------------------------------------------
// kernel3: class softmax + assemble output
// reduced arrays are in fragment order: elem(q,t) at
//   (b*7 + q>>4)*1024 + (((q&15)>>2)*16 + (t&15))*16 + (t>>4)*4 + (q&3)
// ---------------------------------------------------------------------------
__device__ __forceinline__ size_t ridx(int b, int q, int t) {
  return (size_t)(b*7 + (q >> 4))*1024
       + (size_t)((((q & 15) >> 2)*16 + (t & 15))*16 + (t >> 4)*4 + (q & 3));
}

__global__ __launch_bounds__(64) void finalize_k(
    const float* __restrict__ cls, const int* __restrict__ labels,
    const float* __restrict__ ssp, const float* __restrict__ rm,
    const float* __restrict__ rs, float* __restrict__ out) {
  int blk = blockIdx.x;
  int b = blk / NQ, q = blk % NQ;
  int lane = threadIdx.x;
  const float* lgt = cls + (size_t)(b*NQ + q) * NL;
  float v = (lane < NL) ? lgt[lane] : -1e30f;
  float mx = v;
  for (int s = 32; s; s >>= 1) mx = fmaxf(mx, __shfl_xor(mx, s));
  float e = (lane < NL) ? __expf(v - mx) : 0.f;
  float se = e;
  for (int s = 32; s; s >>= 1) se += __shfl_xor(se, s);

  if (lane < NT) {
    int lbl = labels[b*NT + lane];
    float p = __expf(lgt[lbl] - mx) / se;               // softmax prob at label
    // Sum softplus(m) = Sum m (ones col) + ln2 * Sum log2(1+e^-m)
    float s1 = rm[ridx(b, q, 63)] + 0.69314718056f * ssp[b*QP + q];
    float sg = rs[ridx(b, q, 63)];                      // Sum sigmoid
    float msum = rm[ridx(b, 111, lane)];                // Sum mask (ones row)
    float dm = rm[ridx(b, q, lane)];
    float ds = rs[ridx(b, q, lane)];
    float cmask = (s1 - dm) * (1.f / (float)NG);
    float cdice = 1.f - (2.f*ds + 1.f) / (sg + msum + 1.f);
    out[(size_t)(b*NQ + q)*NT + lane] = cmask - p + cdice;
  }
}

// ============================================================================
extern "C" void kernel_launch(void* const* d_in, const int* in_sizes, int n_in,
                              void* d_out, int out_size, void* d_ws, size_t ws_size,
                              hipStream_t stream) {
  const float* mq = (const float*)d_in[0];   // [16,100,16384]
  const float* cq = (const float*)d_in[1];   // [16,100,21]
  const float* ml = (const float*)d_in[2];   // [16,50,16384]
  const int*   cl = (const int*)d_in[3];     // [16,50]
  char* ws = (char*)d_ws;
  float* pdm = (float*)(ws + OFF_PM);
  float* pds = (float*)(ws + OFF_PS);
  float* rm  = (float*)(ws + OFF_RM);
  float* rs  = (float*)(ws + OFF_RS);
  float* ssp = (float*)(ws + OFF_SSP);

  hipMemsetAsync(ssp, 0, SZ_SSP, stream);
  gemm_part<<<NB*NCH, 448, 0, stream>>>(mq, ml, ssp, pdm, pds);
  reduce_k<<<448, 256, 0, stream>>>(pdm, pds, rm, rs);
  finalize_k<<<NB*NQ, 64, 0, stream>>>(cq, cl, ssp, rm, rs, (float*)d_out);
}